// Round 13
// baseline (1522.542 us; speedup 1.0000x reference)
//
#include <hip/hip_runtime.h>
#include <hip/hip_bf16.h>
#include <math.h>

constexpr int kV = 32000;
constexpr int kD = 512;
constexpr int kC = 2;
constexpr int kS = 2048;
constexpr int kL = 4;
constexpr int kM = 64;
constexpr int kB = 16;
constexpr int kH = 2048;
constexpr int kBS = kB * kS; // 32768
constexpr int kSplits = 16;  // kvh S-splits (8 regressed: 1 block/CU)

typedef __hip_bfloat16 bf16;
using bf16x8 = __attribute__((ext_vector_type(8))) short;
using f32x4  = __attribute__((ext_vector_type(4))) float;

#define GLOBAL_LOAD_LDS16(gp, lp)                                              \
  __builtin_amdgcn_global_load_lds(                                            \
      (const __attribute__((address_space(1))) void*)(gp),                     \
      (__attribute__((address_space(3))) void*)(lp), 16, 0, 0)

__device__ inline unsigned short f2bf_u16(float f) {
  bf16 b = __float2bfloat16(f);
  return *reinterpret_cast<unsigned short*>(&b);
}

// ---------------------------------------------------------------------------
__global__ __launch_bounds__(256) void embed_kernel(const int* __restrict__ x,
    const float* __restrict__ emb, const float* __restrict__ pos,
    float* __restrict__ h, bf16* __restrict__ hb) {
  int tid = blockIdx.x * 256 + threadIdx.x;
  int row = tid >> 7;
  int d4  = tid & 127;
  int tok = x[row];
  int s   = row & (kS - 1);
  float4 e = ((const float4*)emb)[(size_t)tok * 128 + d4];
  float4 p = ((const float4*)pos)[(size_t)s * 128 + d4];
  float4 o;
  o.x = e.x + p.x; o.y = e.y + p.y; o.z = e.z + p.z; o.w = e.w + p.w;
  ((float4*)h)[(size_t)row * 128 + d4] = o;
  ushort4 ub;
  ub.x = f2bf_u16(o.x); ub.y = f2bf_u16(o.y);
  ub.z = f2bf_u16(o.z); ub.w = f2bf_u16(o.w);
  ((ushort4*)hb)[(size_t)row * 128 + d4] = ub;
}

// ---------------------------------------------------------------------------
// Batched (z = layer) transpose+cast.
__global__ __launch_bounds__(256) void transpose_cast_kernel(
    const float* __restrict__ W, bf16* __restrict__ Wt, int K, int N,
    size_t zsW, size_t zsWt) {
  __shared__ float tile[32][33];
  W  += zsW  * blockIdx.z;
  Wt += zsWt * blockIdx.z;
  const int k0 = blockIdx.x * 32, n0 = blockIdx.y * 32;
  int tx = threadIdx.x & 31, ty = threadIdx.x >> 5;
#pragma unroll
  for (int i = 0; i < 32; i += 8)
    tile[ty + i][tx] = W[(size_t)(k0 + ty + i) * N + n0 + tx];
  __syncthreads();
#pragma unroll
  for (int i = 0; i < 32; i += 8)
    Wt[(size_t)(n0 + ty + i) * K + k0 + tx] = __float2bfloat16(tile[tx][ty + i]);
}

__global__ __launch_bounds__(256) void cast_bf16_kernel(
    const float* __restrict__ src, bf16* __restrict__ dst) {
  int gid = blockIdx.x * 256 + threadIdx.x;
  float4 v = ((const float4*)src)[gid];
  ushort4 u;
  u.x = f2bf_u16(v.x); u.y = f2bf_u16(v.y);
  u.z = f2bf_u16(v.z); u.w = f2bf_u16(v.w);
  ((ushort4*)dst)[gid] = u;
}

__global__ __launch_bounds__(256) void zero512_kernel(float* __restrict__ p) {
  if (threadIdx.x < 128) ((float4*)p)[threadIdx.x] = make_float4(0.f, 0.f, 0.f, 0.f);
}

// ---------------------------------------------------------------------------
// Fold Wq and Wk with P for ALL layers in one launch: 262144 threads.
__global__ __launch_bounds__(256) void wfold_dual_kernel(
    const float* __restrict__ Wq, const float* __restrict__ Wk,
    const float* __restrict__ P, bf16* __restrict__ Wqpt,
    bf16* __restrict__ Wkpt) {
  int gid = blockIdx.x * 256 + threadIdx.x;       // 0..262143
  int l   = gid >> 16;
  int id  = gid & 65535;
  const float* Pl = P + (size_t)l * kD * kM;
  const float* W  = ((id < 32768) ? Wq : Wk) + (size_t)l * kD * kD;
  bf16* out       = ((id < 32768) ? Wqpt : Wkpt) + (size_t)l * kM * kD;
  id &= 32767;
  int m  = id & 63;
  int kk = id >> 6;
  float a0 = 0.f, a1 = 0.f, a2 = 0.f, a3 = 0.f;
#pragma unroll 4
  for (int c = 0; c < kD; c += 4) {
    float4 w = *(const float4*)&W[(size_t)kk * kD + c];
    a0 = fmaf(w.x, Pl[(size_t)(c + 0) * kM + m], a0);
    a1 = fmaf(w.y, Pl[(size_t)(c + 1) * kM + m], a1);
    a2 = fmaf(w.z, Pl[(size_t)(c + 2) * kM + m], a2);
    a3 = fmaf(w.w, Pl[(size_t)(c + 3) * kM + m], a3);
  }
  out[(size_t)m * kD + kk] = __float2bfloat16((a0 + a1) + (a2 + a3));
}

// All 4 layers in one 512-thread block.
__global__ __launch_bounds__(512) void bfold_kernel(const float* __restrict__ bq,
    const float* __restrict__ bk, const float* __restrict__ P,
    float* __restrict__ bqp, float* __restrict__ bkp) {
  int l = threadIdx.x >> 7;
  int t = threadIdx.x & 127;
  int m = t & (kM - 1);
  const float* Pl  = P + (size_t)l * kD * kM;
  const float* src = ((t >> 6) ? bk : bq) + (size_t)l * kD;
  float* dst       = ((t >> 6) ? bkp : bqp) + (size_t)l * kM;
  float acc = 0.f;
  for (int c = 0; c < kD; ++c) acc += src[c] * Pl[(size_t)c * kM + m];
  dst[m] = acc;
}

// Batched bv @ Wo: blockIdx.y = layer.
__global__ __launch_bounds__(256) void bvwo_kernel(const float* __restrict__ bv,
    const float* __restrict__ Wo, float* __restrict__ bvWo) {
  __shared__ float part[4][64];
  int l = blockIdx.y;
  bv   += (size_t)l * kD;
  Wo   += (size_t)l * kD * kD;
  bvWo += (size_t)l * kD;
  int d0 = blockIdx.x * 64;
  int dc = threadIdx.x & 63;
  int eg = threadIdx.x >> 6;  // 0..3
  float acc = 0.f;
  int e0 = eg * 128;
#pragma unroll 4
  for (int e = e0; e < e0 + 128; ++e)
    acc = fmaf(bv[e], Wo[(size_t)e * kD + d0 + dc], acc);
  part[eg][dc] = acc;
  __syncthreads();
  if (eg == 0)
    bvWo[d0 + dc] = (part[0][dc] + part[1][dc]) + (part[2][dc] + part[3][dc]);
}

// ---------------------------------------------------------------------------
// bf16 MFMA GEMM, tile 128 x BN (128|64), BK in {32,64}, 256 threads.
// SINGLE-buffer 2-barrier structure. Small/medium GEMMs; batched via z.
// ---------------------------------------------------------------------------
template <int BK, int BN, int ACT, bool HAS_RES, bool HAS_OUTER, bool WRITE_F32, bool WRITE_BF16>
__global__ __launch_bounds__(256) void mfma_gemm(
    const bf16* __restrict__ A, const bf16* __restrict__ Wt,
    const float* __restrict__ bias, const float* __restrict__ rowv,
    const float* __restrict__ colv, const float* __restrict__ res,
    float* __restrict__ C, bf16* __restrict__ Cb,
    size_t zsA, size_t zsB, size_t zsC, int K, int N) {
  constexpr int NJ = BN / 32;
  constexpr int CPR = BK / 8;            // 16B chunks per row
  constexpr int SW = (BK == 32) ? 1 : 0; // swizzle shift
  __shared__ short As[128 * BK];
  __shared__ short Bs[BN * BK];
  A  += zsA * blockIdx.z;
  Wt += zsB * blockIdx.z;
  if (C)  C  += zsC * blockIdx.z;
  if (Cb) Cb += zsC * blockIdx.z;
  const int tid  = threadIdx.x;
  const int lane = tid & 63;
  const int wave = tid >> 6;
  const int nx = gridDim.x;
  const int SH = (gridDim.y & 7) ? gridDim.y : 8;
  const int b_lin = blockIdx.y * nx + blockIdx.x;
  const int stripe = b_lin / (nx * SH);
  const int rem = b_lin - stripe * (nx * SH);
  const int row0 = (stripe * SH + (rem % SH)) * 128;
  const int col0 = (rem / SH) * BN;
  const int wr = (wave & 1) * 64;
  const int wc = (wave >> 1) * (BN / 2);
  const int lcol = lane & 15;
  const int quad = lane >> 4;

  f32x4 acc[4][NJ];
#pragma unroll
  for (int i = 0; i < 4; ++i)
#pragma unroll
    for (int j = 0; j < NJ; ++j) acc[i][j] = (f32x4){0.f, 0.f, 0.f, 0.f};

  for (int k0 = 0; k0 < K; k0 += BK) {
#pragma unroll
    for (int p = 0; p < 128 * CPR / 256; ++p) {
      int idx = p * 256 + tid;
      int r = idx / CPR;
      int kc = (idx % CPR) ^ ((r >> SW) & (CPR - 1));
      GLOBAL_LOAD_LDS16(&A[(size_t)(row0 + r) * K + k0 + kc * 8], &As[idx * 8]);
    }
#pragma unroll
    for (int p = 0; p < BN * CPR / 256; ++p) {
      int idx = p * 256 + tid;
      int r = idx / CPR;
      int kc = (idx % CPR) ^ ((r >> SW) & (CPR - 1));
      GLOBAL_LOAD_LDS16(&Wt[(size_t)(col0 + r) * K + k0 + kc * 8], &Bs[idx * 8]);
    }
    __syncthreads();
#pragma unroll
    for (int kh = 0; kh < BK / 32; ++kh) {
      bf16x8 af[4], bfr[NJ];
#pragma unroll
      for (int i = 0; i < 4; ++i) {
        int rr = wr + i * 16 + lcol;
        int slot = (kh * 4 + quad) ^ ((rr >> SW) & (CPR - 1));
        af[i] = *(const bf16x8*)&As[(rr * CPR + slot) * 8];
      }
#pragma unroll
      for (int j = 0; j < NJ; ++j) {
        int rr = wc + j * 16 + lcol;
        int slot = (kh * 4 + quad) ^ ((rr >> SW) & (CPR - 1));
        bfr[j] = *(const bf16x8*)&Bs[(rr * CPR + slot) * 8];
      }
#pragma unroll
      for (int i = 0; i < 4; ++i)
#pragma unroll
        for (int j = 0; j < NJ; ++j)
          acc[i][j] = __builtin_amdgcn_mfma_f32_16x16x32_bf16(af[i], bfr[j], acc[i][j], 0, 0, 0);
    }
    __syncthreads();
  }

#pragma unroll
  for (int i = 0; i < 4; ++i) {
#pragma unroll
    for (int r = 0; r < 4; ++r) {
      int grow = row0 + wr + i * 16 + quad * 4 + r;
#pragma unroll
      for (int j = 0; j < NJ; ++j) {
        int gcol = col0 + wc + j * 16 + lcol;
        float v = acc[i][j][r];
        if (HAS_OUTER) v += rowv[grow] * colv[gcol];
        else v += bias[gcol];
        if (ACT == 2) v = 0.5f * v * (1.0f + erff(v * 0.70710678118654752f));
        size_t off = (size_t)grow * N + gcol;
        if (HAS_RES) v += res[off];
        if (WRITE_F32) C[off] = v;
        if (WRITE_BF16) Cb[off] = __float2bfloat16(v);
      }
    }
  }
}

// ---------------------------------------------------------------------------
// COUNTED-VMCNT pipelined FFN GEMM (T3+T4): 128x128 tile, BK=64, 512 threads,
// depth-2 prefetch, vmcnt(4) steady state. NEW this round:
//  - 2D-chunked XCD swizzle (T1): xcd = b_lin&7 owns a contiguous band of
//    ny/8 row-blocks x ALL cols, so one XCD's L2 holds its A-band (2MB) plus
//    the full B panel set (2MB) -> cross-XCD re-fetch eliminated (W1 FETCH
//    was 30MB vs 18MB ideal). Pure block-index bijection (needs nwg%8==0 and
//    ny%8==0: W1 (16,128), W2 (4,128) both OK).
//  - T5 setprio(1/0) around the MFMA cluster (pre-commit: null=inconclusive
//    on this 2ph-like structure per m190/m230).
// ---------------------------------------------------------------------------
template <int ACT, bool HAS_RES, bool WRITE_F32, bool WRITE_BF16>
__global__ __launch_bounds__(512) void mfma_gemm_cnt(
    const bf16* __restrict__ A, const bf16* __restrict__ Wt,
    const float* __restrict__ bias, const float* __restrict__ res,
    float* __restrict__ C, bf16* __restrict__ Cb, int K, int N) {
  constexpr int BK = 64, BN = 128, BM = 128;
  __shared__ short As[2][BM * BK];
  __shared__ short Bs[2][BN * BK];
  const int tid  = threadIdx.x;
  const int lane = tid & 63;
  const int wave = tid >> 6;           // 0..7
  const int nx = gridDim.x;
  const int b_lin = blockIdx.y * nx + blockIdx.x;
  const int xcd = b_lin & 7;
  const int idx = b_lin >> 3;
  const int row0 = (xcd * (gridDim.y >> 3) + idx / nx) * BM;
  const int col0 = (idx % nx) * BN;
  const int wr = (wave & 1) * 64;
  const int wc = (wave >> 1) * 32;
  const int lcol = lane & 15;
  const int quad = lane >> 4;

  f32x4 acc[4][2];
#pragma unroll
  for (int i = 0; i < 4; ++i)
#pragma unroll
    for (int j = 0; j < 2; ++j) acc[i][j] = (f32x4){0.f, 0.f, 0.f, 0.f};

  auto stage = [&](int buf, int k0) {   // 4 global_load_lds per thread
#pragma unroll
    for (int p = 0; p < 2; ++p) {
      int i2 = p * 512 + tid;
      int r = i2 >> 3;
      int kc = (i2 & 7) ^ (r & 7);
      GLOBAL_LOAD_LDS16(&A[(size_t)(row0 + r) * K + k0 + kc * 8], &As[buf][i2 * 8]);
    }
#pragma unroll
    for (int p = 0; p < 2; ++p) {
      int i2 = p * 512 + tid;
      int r = i2 >> 3;
      int kc = (i2 & 7) ^ (r & 7);
      GLOBAL_LOAD_LDS16(&Wt[(size_t)(col0 + r) * K + k0 + kc * 8], &Bs[buf][i2 * 8]);
    }
  };

  auto compute = [&](int buf) {
#pragma unroll
    for (int kh = 0; kh < 2; ++kh) {
      bf16x8 af[4], bfr[2];
#pragma unroll
      for (int i = 0; i < 4; ++i) {
        int rr = wr + i * 16 + lcol;
        int slot = (kh * 4 + quad) ^ (rr & 7);
        af[i] = *(const bf16x8*)&As[buf][(rr * 8 + slot) * 8];
      }
#pragma unroll
      for (int j = 0; j < 2; ++j) {
        int rr = wc + j * 16 + lcol;
        int slot = (kh * 4 + quad) ^ (rr & 7);
        bfr[j] = *(const bf16x8*)&Bs[buf][(rr * 8 + slot) * 8];
      }
      __builtin_amdgcn_s_setprio(1);
#pragma unroll
      for (int i = 0; i < 4; ++i)
#pragma unroll
        for (int j = 0; j < 2; ++j)
          acc[i][j] = __builtin_amdgcn_mfma_f32_16x16x32_bf16(af[i], bfr[j], acc[i][j], 0, 0, 0);
      __builtin_amdgcn_s_setprio(0);
    }
  };

  const int NT = K / BK;                // >= 2 for all uses (8 or 32)
  stage(0, 0);
  stage(1, BK);                         // 8 loads/thread in flight
  for (int t = 0; t < NT - 1; ++t) {
    const int cur = t & 1;
    asm volatile("s_waitcnt vmcnt(4)" ::: "memory");  // oldest 4 = buf cur
    __builtin_amdgcn_s_barrier();
    compute(cur);
    __builtin_amdgcn_s_barrier();       // all waves done reading buf cur
    if (t + 2 < NT) stage(cur, (t + 2) * BK);
  }
  asm volatile("s_waitcnt vmcnt(0)" ::: "memory");    // last tile's 4 loads
  __builtin_amdgcn_s_barrier();
  compute((NT - 1) & 1);

#pragma unroll
  for (int i = 0; i < 4; ++i) {
#pragma unroll
    for (int r = 0; r < 4; ++r) {
      int grow = row0 + wr + i * 16 + quad * 4 + r;
#pragma unroll
      for (int j = 0; j < 2; ++j) {
        int gcol = col0 + wc + j * 16 + lcol;
        float v = acc[i][j][r] + bias[gcol];
        if (ACT == 2) v = 0.5f * v * (1.0f + erff(v * 0.70710678118654752f));
        size_t off = (size_t)grow * N + gcol;
        if (HAS_RES) v += res[off];
        if (WRITE_F32) C[off] = v;
        if (WRITE_BF16) Cb[off] = __float2bfloat16(v);
      }
    }
  }
}

// ---------------------------------------------------------------------------
// Dual skinny MFMA GEMM, counted-vmcnt depth-2 pipeline. 64-row tile,
// K=512 -> 16 steps. LDS 2x12KB = 24KB. Block 0 also zeroes pks (4KB) at
// start — replaces the standalone zero_pks launch (stream order guarantees
// visibility before kvh_split's atomics).
// pq = elu(A@Wq^T + bq)+1 AND pk = elu(A@Wk^T + bk)+1.
// ---------------------------------------------------------------------------
__global__ __launch_bounds__(256) void skinny_dual_gemm(
    const bf16* __restrict__ A, const bf16* __restrict__ Wq,
    const bf16* __restrict__ Wk, const float* __restrict__ bq,
    const float* __restrict__ bk, float* __restrict__ pq,
    float* __restrict__ pk, float* __restrict__ pks) {
  __shared__ short As[2][64 * 32];
  __shared__ short Bs[2][128 * 32];
  const int tid  = threadIdx.x;
  const int lane = tid & 63;
  const int wave = tid >> 6;
  const int row0 = blockIdx.x * 64;
  const int lcol = lane & 15;
  const int quad = lane >> 4;

  if (blockIdx.x == 0)
    ((float4*)pks)[tid] = make_float4(0.f, 0.f, 0.f, 0.f);   // kB*kM = 1024 f32

  f32x4 accq[4], acck[4];
#pragma unroll
  for (int i = 0; i < 4; ++i) {
    accq[i] = (f32x4){0.f, 0.f, 0.f, 0.f};
    acck[i] = (f32x4){0.f, 0.f, 0.f, 0.f};
  }

  auto stage = [&](int buf, int k0) {   // 3 global_load_lds per thread
    {
      int r = tid >> 2;
      int kc = (tid & 3) ^ ((r >> 1) & 3);
      GLOBAL_LOAD_LDS16(&A[(size_t)(row0 + r) * kD + k0 + kc * 8], &As[buf][tid * 8]);
    }
#pragma unroll
    for (int p = 0; p < 2; ++p) {
      int idx = p * 256 + tid;
      int r = idx >> 2;
      int kc = (idx & 3) ^ ((r >> 1) & 3);
      const bf16* src = (r < 64) ? &Wq[(size_t)r * kD + k0 + kc * 8]
                                 : &Wk[(size_t)(r - 64) * kD + k0 + kc * 8];
      GLOBAL_LOAD_LDS16(src, &Bs[buf][idx * 8]);
    }
  };

  auto compute = [&](int buf) {
    bf16x8 af[4], bq_f, bk_f;
#pragma unroll
    for (int i = 0; i < 4; ++i) {
      int rr = i * 16 + lcol;
      af[i] = *(const bf16x8*)&As[buf][(rr * 4 + (quad ^ ((rr >> 1) & 3))) * 8];
    }
    {
      int rr = wave * 16 + lcol;
      bq_f = *(const bf16x8*)&Bs[buf][(rr * 4 + (quad ^ ((rr >> 1) & 3))) * 8];
      int rr2 = 64 + wave * 16 + lcol;
      bk_f = *(const bf16x8*)&Bs[buf][(rr2 * 4 + (quad ^ ((rr2 >> 1) & 3))) * 8];
    }
    __builtin_amdgcn_s_setprio(1);
#pragma unroll
    for (int i = 0; i < 4; ++i) {
      accq[i] = __builtin_amdgcn_mfma_f32_16x16x32_bf16(af[i], bq_f, accq[i], 0, 0, 0);
      acck[i] = __builtin_amdgcn_mfma_f32_16x16x32_bf16(af[i], bk_f, acck[i], 0, 0, 0);
    }
    __builtin_amdgcn_s_setprio(0);
  };

  const int NT = kD / 32;               // 16
  stage(0, 0);
  stage(1, 32);                         // 6 loads/thread in flight
  for (int t = 0; t < NT - 1; ++t) {
    const int cur = t & 1;
    asm volatile("s_waitcnt vmcnt(3)" ::: "memory");  // oldest 3 = buf cur
    __builtin_amdgcn_s_barrier();
    compute(cur);
    __builtin_amdgcn_s_barrier();
    if (t + 2 < NT) stage(cur, (t + 2) * 32);
  }
  asm volatile("s_waitcnt vmcnt(0)" ::: "memory");
  __builtin_amdgcn_s_barrier();
  compute((NT - 1) & 1);

#pragma unroll
  for (int i = 0; i < 4; ++i) {
#pragma unroll
    for (int r = 0; r < 4; ++r) {
      int grow = row0 + i * 16 + quad * 4 + r;
      int gcol = wave * 16 + lcol;
      float vq = accq[i][r] + bq[gcol];
      vq = (vq > 0.f) ? (vq + 1.f) : expf(vq);
      pq[(size_t)grow * kM + gcol] = vq;
      float vk = acck[i][r] + bk[gcol];
      vk = (vk > 0.f) ? (vk + 1.f) : expf(vk);
      pk[(size_t)grow * kM + gcol] = vk;
    }
  }
}

// ---------------------------------------------------------------------------
// kvh split: 16 S-splits (128 s-rows each; 512 blocks = 2/CU). pksum folded
// (d0==0 block accumulates pk column sums; pks zeroed by skinny_dual).
// f32 LDS staging (VGPR ~72) with conflict-free contiguous read mapping
// j*64+tx*4 (round-12: bank conflicts -> 0, back at best-tier total).
// ---------------------------------------------------------------------------
__global__ __launch_bounds__(256) void kvh_split_kernel(const float* __restrict__ pk,
    const bf16* __restrict__ hb, float* __restrict__ part,
    float* __restrict__ pks) {
  __shared__ float pkS[16][64];
  __shared__ float vS[16][256];
  const int d0 = blockIdx.x * 256, b = blockIdx.y, split = blockIdx.z;
  const int s_beg = split * (kS / kSplits);           // 128 rows per split
  const float* pkb = pk + (size_t)b * kS * kM;
  const bf16* hbb  = hb + (size_t)b * kS * kD;
  const int tid = threadIdx.x;
  const int tx = tid & 15, ty = tid >> 4;
  const bool do_pks = (blockIdx.x == 0);
  float lsum0 = 0.f, lsum1 = 0.f, lsum2 = 0.f, lsum3 = 0.f;
  const int mc = (tid * 4) & 63;
  float4 acc[4][4];
#pragma unroll
  for (int i = 0; i < 4; ++i)
#pragma unroll
    for (int j = 0; j < 4; ++j) acc[i][j] = make_float4(0.f, 0.f, 0.f, 0.f);

  for (int s0 = s_beg; s0 < s_beg + kS / kSplits; s0 += 16) {
    {
      int sr = tid >> 4;
      float4 v = *(const float4*)&pkb[(size_t)(s0 + sr) * kM + mc];
      *(float4*)&pkS[sr][mc] = v;
      if (do_pks) { lsum0 += v.x; lsum1 += v.y; lsum2 += v.z; lsum3 += v.w; }
    }
#pragma unroll
    for (int p = 0; p < 2; ++p) {
      int idx = p * 256 + tid;
      int sr = idx >> 5, dc8 = idx & 31;
      uint4 raw = *(const uint4*)&hbb[(size_t)(s0 + sr) * kD + d0 + dc8 * 8];
      float4 f0, f1;
      f0.x = __uint_as_float(raw.x << 16);
      f0.y = __uint_as_float(raw.x & 0xffff0000u);
      f0.z = __uint_as_float(raw.y << 16);
      f0.w = __uint_as_float(raw.y & 0xffff0000u);
      f1.x = __uint_as_float(raw.z << 16);
      f1.y = __uint_as_float(raw.z & 0xffff0000u);
      f1.z = __uint_as_float(raw.w << 16);
      f1.w = __uint_as_float(raw.w & 0xffff0000u);
      *(float4*)&vS[sr][dc8 * 8]     = f0;
      *(float4*)&vS[sr][dc8 * 8 + 4] = f1;
    }
    __syncthreads();
#pragma unroll
    for (int sr = 0; sr < 16; ++sr) {
      float a[4];
#pragma unroll
      for (int i = 0; i < 4; ++i) a[i] = pkS[sr][ty * 4 + i];
      float4 bv4[4];
#pragma unroll
      for (int j = 0; j < 4; ++j) bv4[j] = *(const float4*)&vS[sr][j * 64 + tx * 4];
#pragma unroll
      for (int i = 0; i < 4; ++i)
#pragma unroll
        for (int j = 0; j < 4; ++j) {
          acc[i][j].x += a[i] * bv4[j].x;
          acc[i][j].y += a[i] * bv4[j].y;
          acc[i][j].z += a[i] * bv4[j].z;
          acc[i][j].w += a[i] * bv4[j].w;
        }
    }
    __syncthreads();
  }
  if (do_pks) {
    atomicAdd(&pks[b * kM + mc + 0], lsum0);
    atomicAdd(&pks[b * kM + mc + 1], lsum1);
    atomicAdd(&pks[b * kM + mc + 2], lsum2);
    atomicAdd(&pks[b * kM + mc + 3], lsum3);
  }
  float* pp = part + (((size_t)split * kB + b) * kM) * kD;
#pragma unroll
  for (int i = 0; i < 4; ++i)
#pragma unroll
    for (int j = 0; j < 4; ++j)
      *(float4*)&pp[(size_t)(ty * 4 + i) * kD + d0 + j * 64 + tx * 4] = acc[i][j];
}

__global__ __launch_bounds__(256) void kvh_reduce_kernel(const float* __restrict__ part,
                                                         bf16* __restrict__ kvhb) {
  int gid = blockIdx.x * 256 + threadIdx.x;
  float4 s = make_float4(0.f, 0.f, 0.f, 0.f);
#pragma unroll
  for (int sp = 0; sp < kSplits; ++sp) {
    float4 p = ((const float4*)part)[(size_t)sp * (kB * kM * kD / 4) + gid];
    s.x += p.x; s.y += p.y; s.z += p.z; s.w += p.w;
  }
  ushort4 u;
  u.x = f2bf_u16(s.x); u.y = f2bf_u16(s.y);
  u.z = f2bf_u16(s.z); u.w = f2bf_u16(s.w);
  ((ushort4*)kvhb)[gid] = u;
}

// ---------------------------------------------------------------------------
// Fused attention-output + z + LayerNorm.
// ---------------------------------------------------------------------------
__global__ __launch_bounds__(256) void att_ln_kernel(
    const float* __restrict__ pq, const float* __restrict__ kvo,
    const float* __restrict__ pks, const float* __restrict__ bo,
    const float* __restrict__ g, const float* __restrict__ bb,
    bf16* __restrict__ out) {
  __shared__ float pqS[32][68];
  __shared__ float kvS[16][520];
  const int s0 = blockIdx.x * 32, b = blockIdx.y;
  const int tid = threadIdx.x;
  const int tx = tid & 15, ty = tid >> 4;

#pragma unroll
  for (int i = 0; i < 2; ++i) {
    int f4 = tid + i * 256;
    int r = f4 >> 4, c = (f4 & 15) * 4;
    *(float4*)&pqS[r][c] = *(const float4*)&pq[((size_t)(b * kS + s0 + r)) * kM + c];
  }

  float4 acc[2][8];
#pragma unroll
  for (int i = 0; i < 2; ++i)
#pragma unroll
    for (int j = 0; j < 8; ++j) acc[i][j] = make_float4(0.f, 0.f, 0.f, 0.f);

  for (int m0 = 0; m0 < kM; m0 += 16) {
#pragma unroll
    for (int p = 0; p < 8; ++p) {
      int idx = p * 256 + tid;
      int sr = idx >> 7, c4 = idx & 127;
      *(float4*)&kvS[sr][c4 * 4] =
          *(const float4*)&kvo[((size_t)b * kM + m0 + sr) * kD + c4 * 4];
    }
    __syncthreads();
#pragma unroll
    for (int mm = 0; mm < 16; ++mm) {
      float a0 = pqS[ty * 2 + 0][m0 + mm];
      float a1 = pqS[ty * 2 + 1][m0 + mm];
#pragma unroll
      for (int j = 0; j < 8; ++j) {
        float4 bv = *(const float4*)&kvS[mm][j * 64 + tx * 4];
        acc[0][j].x += a0 * bv.x; acc[0][j].y += a0 * bv.y;
        acc[0][j].z += a0 * bv.z; acc[0][j].w += a0 * bv.w;
        acc[1][j].x += a1 * bv.x; acc[1][j].y += a1 * bv.y;
        acc[1][j].z += a1 * bv.z; acc[1][j].w += a1 * bv.w;
      }
    }
    __syncthreads();
  }

  // z inline: each of the row's 16 lanes covers 4 m-values, 16-lane reduce.
  float4 pk4 = *(const float4*)&pks[b * kM + tx * 4];
  float z0 = pqS[ty * 2 + 0][tx * 4 + 0] * pk4.x + pqS[ty * 2 + 0][tx * 4 + 1] * pk4.y +
             pqS[ty * 2 + 0][tx * 4 + 2] * pk4.z + pqS[ty * 2 + 0][tx * 4 + 3] * pk4.w;
  float z1 = pqS[ty * 2 + 1][tx * 4 + 0] * pk4.x + pqS[ty * 2 + 1][tx * 4 + 1] * pk4.y +
             pqS[ty * 2 + 1][tx * 4 + 2] * pk4.z + pqS[ty * 2 + 1][tx * 4 + 3] * pk4.w;
  z0 += __shfl_xor(z0, 1); z0 += __shfl_xor(z0, 2);
  z0 += __shfl_xor(z0, 4); z0 += __shfl_xor(z0, 8);
  z1 += __shfl_xor(z1, 1); z1 += __shfl_xor(z1, 2);
  z1 += __shfl_xor(z1, 4); z1 += __shfl_xor(z1, 8);
  float zi0 = 1.0f / (z0 + 1e-6f);
  float zi1 = 1.0f / (z1 + 1e-6f);

#pragma unroll
  for (int j = 0; j < 8; ++j) {
    float4 bo4 = *(const float4*)&bo[j * 64 + tx * 4];
    acc[0][j].x = acc[0][j].x * zi0 + bo4.x; acc[0][j].y = acc[0][j].y * zi0 + bo4.y;
    acc[0][j].z = acc[0][j].z * zi0 + bo4.z; acc[0][j].w = acc[0][j].w * zi0 + bo4.w;
    acc[1][j].x = acc[1][j].x * zi1 + bo4.x; acc[1][j].y = acc[1][j].y * zi1 + bo4.y;
    acc[1][j].z = acc[1][j].z * zi1 + bo4.z; acc[1][j].w = acc[1][j].w * zi1 + bo4.w;
  }

#pragma unroll
  for (int i = 0; i < 2; ++i) {
    float s = 0.f;
#pragma unroll
    for (int j = 0; j < 8; ++j)
      s += (acc[i][j].x + acc[i][j].y) + (acc[i][j].z + acc[i][j].w);
    s += __shfl_xor(s, 1); s += __shfl_xor(s, 2);
    s += __shfl_xor(s, 4); s += __shfl_xor(s, 8);
    float mean = s * (1.0f / kD);
    float v2 = 0.f;
#pragma unroll
    for (int j = 0; j < 8; ++j) {
      float dx = acc[i][j].x - mean, dy = acc[i][j].y - mean;
      float dz = acc[i][j].z - mean, dw = acc[i][j].w - mean;
      v2 += (dx * dx + dy * dy) + (dz * dz + dw * dw);
    }
    v2 += __shfl_xor(v2, 1); v2 += __shfl_xor(v2, 2);
    v2 += __shfl_xor(v2, 4); v2 += __shfl_xor(v2, 8);
    float rstd = rsqrtf(v2 * (1.0f / kD) + 1e-5f);
    size_t rowoff = ((size_t)(b * kS + s0 + ty * 2 + i)) * kD;
#pragma unroll
    for (int j = 0; j < 8; ++j) {
      int col = j * 64 + tx * 4;
      float4 g4 = *(const float4*)&g[col];
      float4 b4 = *(const float4*)&bb[col];
      ushort4 u;
      u.x = f2bf_u16((acc[i][j].x - mean) * rstd * g4.x + b4.x);
      u.y = f2bf_u16((acc[i][j].y - mean) * rstd * g4.y + b4.y);
      u.z = f2bf_u16((acc[i][j].z - mean) * rstd * g4.z + b4.z);
      u.w = f2bf_u16((acc[i][j].w - mean) * rstd * g4.w + b4.w);
      *(ushort4*)&out[rowoff + col] = u;
    }
  }
}

// ---------------------------------------------------------------------------
__global__ __launch_bounds__(256) void cls_kernel(const float* __restrict__ h,
    const float* __restrict__ Wc1, const float* __restrict__ bc1,
    const float* __restrict__ Wc2, const float* __restrict__ bc2,
    float* __restrict__ out) {
  __shared__ float r0[4], r1[4];
  int b = blockIdx.x;
  int j = threadIdx.x;
  const float* p = h + (size_t)b * kS * kD;
  float acc = bc1[j];
  for (int i = 0; i < kD; ++i) acc += p[i] * Wc1[i * (kD / 2) + j];
  acc = fmaxf(acc, 0.f);
  float p0 = acc * Wc2[j * kC + 0];
  float p1 = acc * Wc2[j * kC + 1];
#pragma unroll
  for (int off = 32; off; off >>= 1) {
    p0 += __shfl_down(p0, off);
    p1 += __shfl_down(p1, off);
  }
  if ((j & 63) == 0) { r0[j >> 6] = p0; r1[j >> 6] = p1; }
  __syncthreads();
  if (j == 0) {
    out[b * kC + 0] = r0[0] + r0[1] + r0[2] + r0[3] + bc2[0];
    out[b * kC + 1] = r1[0] + r1[1] + r1[2] + r1[3] + bc2[1];
  }
}

// ---------------------------------------------------------------------------
extern "C" void kernel_launch(void* const* d_in, const int* in_sizes, int n_in,
                              void* d_out, int out_size, void* d_ws, size_t ws_size,
                              hipStream_t stream) {
  const int*   x    = (const int*)  d_in[0];
  const float* emb  = (const float*)d_in[1];
  const float* pos  = (const float*)d_in[2];
  const float* Wq   = (const float*)d_in[3];
  const float* bq   = (const float*)d_in[4];
  const float* Wk   = (const float*)d_in[5];
  const float* bk   = (const float*)d_in[6];
  const float* Wv   = (const float*)d_in[7];
  const float* bv   = (const float*)d_in[8];
  const float* P    = (const float*)d_in[9];
  const float* Wo   = (const float*)d_in[10];
  const float* bo   = (const float*)d_in[11];
  const float* ln_g = (const float*)d_in[12];
  const float* ln_b = (const float*)d_in[13];
  const float* W1   = (const float*)d_in[14];
  const float* b1   = (const float*)d_in[15];
  const float* W2   = (const float*)d_in[16];
  const float* b2   = (const float*)d_in[17];
  const float* Wc1  = (const float*)d_in[18];
  const float* bc1  = (const float*)d_in[19];
  const float* Wc2  = (const float*)d_in[20];
  const float* bc2  = (const float*)d_in[21];
  float* out = (float*)d_out;

  // fp32 region
  float* h    = (float*)d_ws;                    // 64 MB
  float* t0   = h    + (size_t)kBS * kD;         // 64 MB (F aliases)
  float* pq   = t0   + (size_t)kBS * kD;         // 8 MB
  float* pk   = pq   + (size_t)kBS * kM;         // 8 MB
  float* kvo  = pk   + (size_t)kBS * kM;         // 2 MB
  float* pks  = kvo  + (size_t)kB * kM * kD;
  float* bqp  = pks  + (size_t)kB * kM;          // kL x kM
  float* bkp  = bqp  + (size_t)kL * kM;
  float* bvWo = bkp  + (size_t)kL * kM;          // kL x kD
  float* zeros= bvWo + (size_t)kL * kD;
  // bf16 region (per-layer weight buffers x kL, prepped once up front)
  bf16* hb    = (bf16*)(zeros + kD);             // 32 MB
  bf16* ab    = hb + (size_t)kBS * kD;           // 32 MB (kvh partials alias)
  bf16* Wqpt  = ab  + (size_t)kBS * kD;
  bf16* Wkpt  = Wqpt + (size_t)kL * kM * kD;
  bf16* Wot   = Wkpt + (size_t)kL * kM * kD;
  bf16* Wvc   = Wot + (size_t)kL * kD * kD;
  bf16* WvWot = Wvc + (size_t)kL * kD * kD;
  bf16* W1t   = WvWot + (size_t)kL * kD * kD;
  bf16* W2t   = W1t + (size_t)kL * kD * kH;
  bf16* kvhb  = W2t + (size_t)kL * kH * kD;
  bf16* F     = (bf16*)t0;
  float* kvpart = (float*)ab;                    // 32 MB (16 splits)

  zero512_kernel<<<1, 256, 0, stream>>>(zeros);
  embed_kernel<<<kBS * (kD / 4) / 256, 256, 0, stream>>>(x, emb, pos, h, hb);

  // ---- batched weight prep for ALL layers ----
  wfold_dual_kernel<<<kL * 256, 256, 0, stream>>>(Wq, Wk, P, Wqpt, Wkpt);
  bfold_kernel<<<1, 128 * kL, 0, stream>>>(bq, bk, P, bqp, bkp);
  transpose_cast_kernel<<<dim3(kD / 32, kD / 32, kL), 256, 0, stream>>>(
      Wo, Wot, kD, kD, (size_t)kD * kD, (size_t)kD * kD);
  cast_bf16_kernel<<<kL * kD * kD / 1024, 256, 0, stream>>>(Wv, Wvc);
  mfma_gemm<32, 64, 0, false, false, false, true><<<dim3(8, 4, kL), 256, 0, stream>>>(
      Wot, Wvc, zeros, nullptr, nullptr, nullptr, nullptr, WvWot,
      (size_t)kD * kD, (size_t)kD * kD, (size_t)kD * kD, kD, kD);
  bvwo_kernel<<<dim3(kD / 64, kL), 256, 0, stream>>>(bv, Wo, bvWo);
  transpose_cast_kernel<<<dim3(kD / 32, kH / 32, kL), 256, 0, stream>>>(
      W1, W1t, kD, kH, (size_t)kD * kH, (size_t)kD * kH);
  transpose_cast_kernel<<<dim3(kH / 32, kD / 32, kL), 256, 0, stream>>>(
      W2, W2t, kH, kD, (size_t)kH * kD, (size_t)kH * kD);

  for (int l = 0; l < kL; ++l) {
    // ---- attention (folded) ----
    skinny_dual_gemm<<<kBS / 64, 256, 0, stream>>>(
        hb, Wqpt + (size_t)l * kM * kD, Wkpt + (size_t)l * kM * kD,
        bqp + (size_t)l * kM, bkp + (size_t)l * kM, pq, pk, pks);
    kvh_split_kernel<<<dim3(kD / 256, kB, kSplits), 256, 0, stream>>>(pk, hb, kvpart, pks);
    kvh_reduce_kernel<<<kB * kM * kD / 1024, 256, 0, stream>>>(kvpart, kvhb);
    mfma_gemm<32, 64, 0, false, true, true, false><<<dim3(8, 8), 256, 0, stream>>>(
        kvhb, WvWot + (size_t)l * kD * kD, nullptr, pks, bvWo + (size_t)l * kD,
        nullptr, kvo, nullptr, 0, 0, 0, kD, kD);
    att_ln_kernel<<<dim3(kS / 32, kB), 256, 0, stream>>>(
        pq, kvo, pks, bo + l * kD, ln_g + l * kD, ln_b + l * kD, ab);
    // ---- FFN in 2 row-chunks of 16384, counted-vmcnt pipelined GEMMs ----
    for (int c = 0; c < 2; ++c) {
      size_t ro = (size_t)c * 16384;
      mfma_gemm_cnt<2, false, false, true><<<dim3(kH / 128, 16384 / 128), 512, 0, stream>>>(
          ab + ro * kD, W1t + (size_t)l * kD * kH, b1 + l * kH, nullptr, nullptr, F, kD, kH);
      mfma_gemm_cnt<0, true, true, true><<<dim3(kD / 128, 16384 / 128), 512, 0, stream>>>(
          F, W2t + (size_t)l * kH * kD, b2 + l * kD, h + ro * kD, h + ro * kD, hb + ro * kD, kH, kD);
    }
  }

  cls_kernel<<<kB, 256, 0, stream>>>(h, Wc1, bc1, Wc2, bc2, out);
}

// Round 14
// 1489.826 us; speedup vs baseline: 1.0220x; 1.0220x over previous
//
#include <hip/hip_runtime.h>
#include <hip/hip_bf16.h>
#include <math.h>

constexpr int kV = 32000;
constexpr int kD = 512;
constexpr int kC = 2;
constexpr int kS = 2048;
constexpr int kL = 4;
constexpr int kM = 64;
constexpr int kB = 16;
constexpr int kH = 2048;
constexpr int kBS = kB * kS; // 32768
constexpr int kSplits = 16;  // kvh S-splits (8 regressed: 1 block/CU)

typedef __hip_bfloat16 bf16;
using bf16x8 = __attribute__((ext_vector_type(8))) short;
using f32x4  = __attribute__((ext_vector_type(4))) float;

#define GLOBAL_LOAD_LDS16(gp, lp)                                              \
  __builtin_amdgcn_global_load_lds(                                            \
      (const __attribute__((address_space(1))) void*)(gp),                     \
      (__attribute__((address_space(3))) void*)(lp), 16, 0, 0)

__device__ inline unsigned short f2bf_u16(float f) {
  bf16 b = __float2bfloat16(f);
  return *reinterpret_cast<unsigned short*>(&b);
}

// ---------------------------------------------------------------------------
__global__ __launch_bounds__(256) void embed_kernel(const int* __restrict__ x,
    const float* __restrict__ emb, const float* __restrict__ pos,
    float* __restrict__ h, bf16* __restrict__ hb) {
  int tid = blockIdx.x * 256 + threadIdx.x;
  int row = tid >> 7;
  int d4  = tid & 127;
  int tok = x[row];
  int s   = row & (kS - 1);
  float4 e = ((const float4*)emb)[(size_t)tok * 128 + d4];
  float4 p = ((const float4*)pos)[(size_t)s * 128 + d4];
  float4 o;
  o.x = e.x + p.x; o.y = e.y + p.y; o.z = e.z + p.z; o.w = e.w + p.w;
  ((float4*)h)[(size_t)row * 128 + d4] = o;
  ushort4 ub;
  ub.x = f2bf_u16(o.x); ub.y = f2bf_u16(o.y);
  ub.z = f2bf_u16(o.z); ub.w = f2bf_u16(o.w);
  ((ushort4*)hb)[(size_t)row * 128 + d4] = ub;
}

// ---------------------------------------------------------------------------
// Batched (z = layer) transpose+cast.
__global__ __launch_bounds__(256) void transpose_cast_kernel(
    const float* __restrict__ W, bf16* __restrict__ Wt, int K, int N,
    size_t zsW, size_t zsWt) {
  __shared__ float tile[32][33];
  W  += zsW  * blockIdx.z;
  Wt += zsWt * blockIdx.z;
  const int k0 = blockIdx.x * 32, n0 = blockIdx.y * 32;
  int tx = threadIdx.x & 31, ty = threadIdx.x >> 5;
#pragma unroll
  for (int i = 0; i < 32; i += 8)
    tile[ty + i][tx] = W[(size_t)(k0 + ty + i) * N + n0 + tx];
  __syncthreads();
#pragma unroll
  for (int i = 0; i < 32; i += 8)
    Wt[(size_t)(n0 + ty + i) * K + k0 + tx] = __float2bfloat16(tile[tx][ty + i]);
}

__global__ __launch_bounds__(256) void cast_bf16_kernel(
    const float* __restrict__ src, bf16* __restrict__ dst) {
  int gid = blockIdx.x * 256 + threadIdx.x;
  float4 v = ((const float4*)src)[gid];
  ushort4 u;
  u.x = f2bf_u16(v.x); u.y = f2bf_u16(v.y);
  u.z = f2bf_u16(v.z); u.w = f2bf_u16(v.w);
  ((ushort4*)dst)[gid] = u;
}

__global__ __launch_bounds__(256) void zero512_kernel(float* __restrict__ p) {
  if (threadIdx.x < 128) ((float4*)p)[threadIdx.x] = make_float4(0.f, 0.f, 0.f, 0.f);
}

// ---------------------------------------------------------------------------
// Fold Wq and Wk with P for ALL layers in one launch: 262144 threads.
__global__ __launch_bounds__(256) void wfold_dual_kernel(
    const float* __restrict__ Wq, const float* __restrict__ Wk,
    const float* __restrict__ P, bf16* __restrict__ Wqpt,
    bf16* __restrict__ Wkpt) {
  int gid = blockIdx.x * 256 + threadIdx.x;       // 0..262143
  int l   = gid >> 16;
  int id  = gid & 65535;
  const float* Pl = P + (size_t)l * kD * kM;
  const float* W  = ((id < 32768) ? Wq : Wk) + (size_t)l * kD * kD;
  bf16* out       = ((id < 32768) ? Wqpt : Wkpt) + (size_t)l * kM * kD;
  id &= 32767;
  int m  = id & 63;
  int kk = id >> 6;
  float a0 = 0.f, a1 = 0.f, a2 = 0.f, a3 = 0.f;
#pragma unroll 4
  for (int c = 0; c < kD; c += 4) {
    float4 w = *(const float4*)&W[(size_t)kk * kD + c];
    a0 = fmaf(w.x, Pl[(size_t)(c + 0) * kM + m], a0);
    a1 = fmaf(w.y, Pl[(size_t)(c + 1) * kM + m], a1);
    a2 = fmaf(w.z, Pl[(size_t)(c + 2) * kM + m], a2);
    a3 = fmaf(w.w, Pl[(size_t)(c + 3) * kM + m], a3);
  }
  out[(size_t)m * kD + kk] = __float2bfloat16((a0 + a1) + (a2 + a3));
}

// All 4 layers in one 512-thread block.
__global__ __launch_bounds__(512) void bfold_kernel(const float* __restrict__ bq,
    const float* __restrict__ bk, const float* __restrict__ P,
    float* __restrict__ bqp, float* __restrict__ bkp) {
  int l = threadIdx.x >> 7;
  int t = threadIdx.x & 127;
  int m = t & (kM - 1);
  const float* Pl  = P + (size_t)l * kD * kM;
  const float* src = ((t >> 6) ? bk : bq) + (size_t)l * kD;
  float* dst       = ((t >> 6) ? bkp : bqp) + (size_t)l * kM;
  float acc = 0.f;
  for (int c = 0; c < kD; ++c) acc += src[c] * Pl[(size_t)c * kM + m];
  dst[m] = acc;
}

// Batched bv @ Wo: blockIdx.y = layer.
__global__ __launch_bounds__(256) void bvwo_kernel(const float* __restrict__ bv,
    const float* __restrict__ Wo, float* __restrict__ bvWo) {
  __shared__ float part[4][64];
  int l = blockIdx.y;
  bv   += (size_t)l * kD;
  Wo   += (size_t)l * kD * kD;
  bvWo += (size_t)l * kD;
  int d0 = blockIdx.x * 64;
  int dc = threadIdx.x & 63;
  int eg = threadIdx.x >> 6;  // 0..3
  float acc = 0.f;
  int e0 = eg * 128;
#pragma unroll 4
  for (int e = e0; e < e0 + 128; ++e)
    acc = fmaf(bv[e], Wo[(size_t)e * kD + d0 + dc], acc);
  part[eg][dc] = acc;
  __syncthreads();
  if (eg == 0)
    bvWo[d0 + dc] = (part[0][dc] + part[1][dc]) + (part[2][dc] + part[3][dc]);
}

// ---------------------------------------------------------------------------
// bf16 MFMA GEMM, tile 128 x BN (128|64), BK in {32,64}, 256 threads.
// SINGLE-buffer 2-barrier structure. Small/medium GEMMs; batched via z.
// ---------------------------------------------------------------------------
template <int BK, int BN, int ACT, bool HAS_RES, bool HAS_OUTER, bool WRITE_F32, bool WRITE_BF16>
__global__ __launch_bounds__(256) void mfma_gemm(
    const bf16* __restrict__ A, const bf16* __restrict__ Wt,
    const float* __restrict__ bias, const float* __restrict__ rowv,
    const float* __restrict__ colv, const float* __restrict__ res,
    float* __restrict__ C, bf16* __restrict__ Cb,
    size_t zsA, size_t zsB, size_t zsC, int K, int N) {
  constexpr int NJ = BN / 32;
  constexpr int CPR = BK / 8;            // 16B chunks per row
  constexpr int SW = (BK == 32) ? 1 : 0; // swizzle shift
  __shared__ short As[128 * BK];
  __shared__ short Bs[BN * BK];
  A  += zsA * blockIdx.z;
  Wt += zsB * blockIdx.z;
  if (C)  C  += zsC * blockIdx.z;
  if (Cb) Cb += zsC * blockIdx.z;
  const int tid  = threadIdx.x;
  const int lane = tid & 63;
  const int wave = tid >> 6;
  const int nx = gridDim.x;
  const int SH = (gridDim.y & 7) ? gridDim.y : 8;
  const int b_lin = blockIdx.y * nx + blockIdx.x;
  const int stripe = b_lin / (nx * SH);
  const int rem = b_lin - stripe * (nx * SH);
  const int row0 = (stripe * SH + (rem % SH)) * 128;
  const int col0 = (rem / SH) * BN;
  const int wr = (wave & 1) * 64;
  const int wc = (wave >> 1) * (BN / 2);
  const int lcol = lane & 15;
  const int quad = lane >> 4;

  f32x4 acc[4][NJ];
#pragma unroll
  for (int i = 0; i < 4; ++i)
#pragma unroll
    for (int j = 0; j < NJ; ++j) acc[i][j] = (f32x4){0.f, 0.f, 0.f, 0.f};

  for (int k0 = 0; k0 < K; k0 += BK) {
#pragma unroll
    for (int p = 0; p < 128 * CPR / 256; ++p) {
      int idx = p * 256 + tid;
      int r = idx / CPR;
      int kc = (idx % CPR) ^ ((r >> SW) & (CPR - 1));
      GLOBAL_LOAD_LDS16(&A[(size_t)(row0 + r) * K + k0 + kc * 8], &As[idx * 8]);
    }
#pragma unroll
    for (int p = 0; p < BN * CPR / 256; ++p) {
      int idx = p * 256 + tid;
      int r = idx / CPR;
      int kc = (idx % CPR) ^ ((r >> SW) & (CPR - 1));
      GLOBAL_LOAD_LDS16(&Wt[(size_t)(col0 + r) * K + k0 + kc * 8], &Bs[idx * 8]);
    }
    __syncthreads();
#pragma unroll
    for (int kh = 0; kh < BK / 32; ++kh) {
      bf16x8 af[4], bfr[NJ];
#pragma unroll
      for (int i = 0; i < 4; ++i) {
        int rr = wr + i * 16 + lcol;
        int slot = (kh * 4 + quad) ^ ((rr >> SW) & (CPR - 1));
        af[i] = *(const bf16x8*)&As[(rr * CPR + slot) * 8];
      }
#pragma unroll
      for (int j = 0; j < NJ; ++j) {
        int rr = wc + j * 16 + lcol;
        int slot = (kh * 4 + quad) ^ ((rr >> SW) & (CPR - 1));
        bfr[j] = *(const bf16x8*)&Bs[(rr * CPR + slot) * 8];
      }
#pragma unroll
      for (int i = 0; i < 4; ++i)
#pragma unroll
        for (int j = 0; j < NJ; ++j)
          acc[i][j] = __builtin_amdgcn_mfma_f32_16x16x32_bf16(af[i], bfr[j], acc[i][j], 0, 0, 0);
    }
    __syncthreads();
  }

#pragma unroll
  for (int i = 0; i < 4; ++i) {
#pragma unroll
    for (int r = 0; r < 4; ++r) {
      int grow = row0 + wr + i * 16 + quad * 4 + r;
#pragma unroll
      for (int j = 0; j < NJ; ++j) {
        int gcol = col0 + wc + j * 16 + lcol;
        float v = acc[i][j][r];
        if (HAS_OUTER) v += rowv[grow] * colv[gcol];
        else v += bias[gcol];
        if (ACT == 2) v = 0.5f * v * (1.0f + erff(v * 0.70710678118654752f));
        size_t off = (size_t)grow * N + gcol;
        if (HAS_RES) v += res[off];
        if (WRITE_F32) C[off] = v;
        if (WRITE_BF16) Cb[off] = __float2bfloat16(v);
      }
    }
  }
}

// ---------------------------------------------------------------------------
// COUNTED-VMCNT pipelined FFN GEMM (T3+T4): 128x128 tile, BK=64, 512 threads,
// depth-2 prefetch, vmcnt(4) in steady state (never drains to 0 mid-loop).
// Measured best of the schedule family (~60us at both FFN shapes).
// SH-stripe swizzle kept (round-13's XCD band remap RAISED FETCH 30->38MB and
// regressed; dispatch->XCD mapping is undefined — do not re-attempt).
// ---------------------------------------------------------------------------
template <int ACT, bool HAS_RES, bool WRITE_F32, bool WRITE_BF16>
__global__ __launch_bounds__(512) void mfma_gemm_cnt(
    const bf16* __restrict__ A, const bf16* __restrict__ Wt,
    const float* __restrict__ bias, const float* __restrict__ res,
    float* __restrict__ C, bf16* __restrict__ Cb, int K, int N) {
  constexpr int BK = 64, BN = 128, BM = 128;
  __shared__ short As[2][BM * BK];
  __shared__ short Bs[2][BN * BK];
  const int tid  = threadIdx.x;
  const int lane = tid & 63;
  const int wave = tid >> 6;           // 0..7
  const int nx = gridDim.x;
  const int SH = (gridDim.y & 7) ? gridDim.y : 8;
  const int b_lin = blockIdx.y * nx + blockIdx.x;
  const int stripe = b_lin / (nx * SH);
  const int rem = b_lin - stripe * (nx * SH);
  const int row0 = (stripe * SH + (rem % SH)) * BM;
  const int col0 = (rem / SH) * BN;
  const int wr = (wave & 1) * 64;
  const int wc = (wave >> 1) * 32;
  const int lcol = lane & 15;
  const int quad = lane >> 4;

  f32x4 acc[4][2];
#pragma unroll
  for (int i = 0; i < 4; ++i)
#pragma unroll
    for (int j = 0; j < 2; ++j) acc[i][j] = (f32x4){0.f, 0.f, 0.f, 0.f};

  auto stage = [&](int buf, int k0) {   // 4 global_load_lds per thread
#pragma unroll
    for (int p = 0; p < 2; ++p) {
      int idx = p * 512 + tid;
      int r = idx >> 3;
      int kc = (idx & 7) ^ (r & 7);
      GLOBAL_LOAD_LDS16(&A[(size_t)(row0 + r) * K + k0 + kc * 8], &As[buf][idx * 8]);
    }
#pragma unroll
    for (int p = 0; p < 2; ++p) {
      int idx = p * 512 + tid;
      int r = idx >> 3;
      int kc = (idx & 7) ^ (r & 7);
      GLOBAL_LOAD_LDS16(&Wt[(size_t)(col0 + r) * K + k0 + kc * 8], &Bs[buf][idx * 8]);
    }
  };

  auto compute = [&](int buf) {
#pragma unroll
    for (int kh = 0; kh < 2; ++kh) {
      bf16x8 af[4], bfr[2];
#pragma unroll
      for (int i = 0; i < 4; ++i) {
        int rr = wr + i * 16 + lcol;
        int slot = (kh * 4 + quad) ^ (rr & 7);
        af[i] = *(const bf16x8*)&As[buf][(rr * 8 + slot) * 8];
      }
#pragma unroll
      for (int j = 0; j < 2; ++j) {
        int rr = wc + j * 16 + lcol;
        int slot = (kh * 4 + quad) ^ (rr & 7);
        bfr[j] = *(const bf16x8*)&Bs[buf][(rr * 8 + slot) * 8];
      }
#pragma unroll
      for (int i = 0; i < 4; ++i)
#pragma unroll
        for (int j = 0; j < 2; ++j)
          acc[i][j] = __builtin_amdgcn_mfma_f32_16x16x32_bf16(af[i], bfr[j], acc[i][j], 0, 0, 0);
    }
  };

  const int NT = K / BK;                // >= 2 for all uses (8 or 32)
  stage(0, 0);
  stage(1, BK);                         // 8 loads/thread in flight
  for (int t = 0; t < NT - 1; ++t) {
    const int cur = t & 1;
    asm volatile("s_waitcnt vmcnt(4)" ::: "memory");  // oldest 4 = buf cur
    __builtin_amdgcn_s_barrier();
    compute(cur);
    __builtin_amdgcn_s_barrier();       // all waves done reading buf cur
    if (t + 2 < NT) stage(cur, (t + 2) * BK);
  }
  asm volatile("s_waitcnt vmcnt(0)" ::: "memory");    // last tile's 4 loads
  __builtin_amdgcn_s_barrier();
  compute((NT - 1) & 1);

#pragma unroll
  for (int i = 0; i < 4; ++i) {
#pragma unroll
    for (int r = 0; r < 4; ++r) {
      int grow = row0 + wr + i * 16 + quad * 4 + r;
#pragma unroll
      for (int j = 0; j < 2; ++j) {
        int gcol = col0 + wc + j * 16 + lcol;
        float v = acc[i][j][r] + bias[gcol];
        if (ACT == 2) v = 0.5f * v * (1.0f + erff(v * 0.70710678118654752f));
        size_t off = (size_t)grow * N + gcol;
        if (HAS_RES) v += res[off];
        if (WRITE_F32) C[off] = v;
        if (WRITE_BF16) Cb[off] = __float2bfloat16(v);
      }
    }
  }
}

// ---------------------------------------------------------------------------
// Dual skinny MFMA GEMM, counted-vmcnt depth-2 pipeline. 64-row tile,
// K=512 -> 16 steps. LDS 2x12KB = 24KB.
// pq = elu(A@Wq^T + bq)+1 AND pk = elu(A@Wk^T + bk)+1.
// ---------------------------------------------------------------------------
__global__ __launch_bounds__(256) void skinny_dual_gemm(
    const bf16* __restrict__ A, const bf16* __restrict__ Wq,
    const bf16* __restrict__ Wk, const float* __restrict__ bq,
    const float* __restrict__ bk, float* __restrict__ pq,
    float* __restrict__ pk) {
  __shared__ short As[2][64 * 32];
  __shared__ short Bs[2][128 * 32];
  const int tid  = threadIdx.x;
  const int lane = tid & 63;
  const int wave = tid >> 6;
  const int row0 = blockIdx.x * 64;
  const int lcol = lane & 15;
  const int quad = lane >> 4;

  f32x4 accq[4], acck[4];
#pragma unroll
  for (int i = 0; i < 4; ++i) {
    accq[i] = (f32x4){0.f, 0.f, 0.f, 0.f};
    acck[i] = (f32x4){0.f, 0.f, 0.f, 0.f};
  }

  auto stage = [&](int buf, int k0) {   // 3 global_load_lds per thread
    {
      int r = tid >> 2;
      int kc = (tid & 3) ^ ((r >> 1) & 3);
      GLOBAL_LOAD_LDS16(&A[(size_t)(row0 + r) * kD + k0 + kc * 8], &As[buf][tid * 8]);
    }
#pragma unroll
    for (int p = 0; p < 2; ++p) {
      int idx = p * 256 + tid;
      int r = idx >> 2;
      int kc = (idx & 3) ^ ((r >> 1) & 3);
      const bf16* src = (r < 64) ? &Wq[(size_t)r * kD + k0 + kc * 8]
                                 : &Wk[(size_t)(r - 64) * kD + k0 + kc * 8];
      GLOBAL_LOAD_LDS16(src, &Bs[buf][idx * 8]);
    }
  };

  auto compute = [&](int buf) {
    bf16x8 af[4], bq_f, bk_f;
#pragma unroll
    for (int i = 0; i < 4; ++i) {
      int rr = i * 16 + lcol;
      af[i] = *(const bf16x8*)&As[buf][(rr * 4 + (quad ^ ((rr >> 1) & 3))) * 8];
    }
    {
      int rr = wave * 16 + lcol;
      bq_f = *(const bf16x8*)&Bs[buf][(rr * 4 + (quad ^ ((rr >> 1) & 3))) * 8];
      int rr2 = 64 + wave * 16 + lcol;
      bk_f = *(const bf16x8*)&Bs[buf][(rr2 * 4 + (quad ^ ((rr2 >> 1) & 3))) * 8];
    }
#pragma unroll
    for (int i = 0; i < 4; ++i) {
      accq[i] = __builtin_amdgcn_mfma_f32_16x16x32_bf16(af[i], bq_f, accq[i], 0, 0, 0);
      acck[i] = __builtin_amdgcn_mfma_f32_16x16x32_bf16(af[i], bk_f, acck[i], 0, 0, 0);
    }
  };

  const int NT = kD / 32;               // 16
  stage(0, 0);
  stage(1, 32);                         // 6 loads/thread in flight
  for (int t = 0; t < NT - 1; ++t) {
    const int cur = t & 1;
    asm volatile("s_waitcnt vmcnt(3)" ::: "memory");  // oldest 3 = buf cur
    __builtin_amdgcn_s_barrier();
    compute(cur);
    __builtin_amdgcn_s_barrier();
    if (t + 2 < NT) stage(cur, (t + 2) * 32);
  }
  asm volatile("s_waitcnt vmcnt(0)" ::: "memory");
  __builtin_amdgcn_s_barrier();
  compute((NT - 1) & 1);

#pragma unroll
  for (int i = 0; i < 4; ++i) {
#pragma unroll
    for (int r = 0; r < 4; ++r) {
      int grow = row0 + i * 16 + quad * 4 + r;
      int gcol = wave * 16 + lcol;
      float vq = accq[i][r] + bq[gcol];
      vq = (vq > 0.f) ? (vq + 1.f) : expf(vq);
      pq[(size_t)grow * kM + gcol] = vq;
      float vk = acck[i][r] + bk[gcol];
      vk = (vk > 0.f) ? (vk + 1.f) : expf(vk);
      pk[(size_t)grow * kM + gcol] = vk;
    }
  }
}

// ---------------------------------------------------------------------------
// kvh split: 16 S-splits (128 s-rows each; 512 blocks = 2/CU). pksum folded
// (d0==0 block accumulates pk column sums; pks zeroed beforehand).
// f32 LDS staging (VGPR ~72) with conflict-free contiguous read mapping
// j*64+tx*4 (round-12: bank conflicts -> 0, best-tier total).
// ---------------------------------------------------------------------------
__global__ __launch_bounds__(256) void kvh_split_kernel(const float* __restrict__ pk,
    const bf16* __restrict__ hb, float* __restrict__ part,
    float* __restrict__ pks) {
  __shared__ float pkS[16][64];
  __shared__ float vS[16][256];
  const int d0 = blockIdx.x * 256, b = blockIdx.y, split = blockIdx.z;
  const int s_beg = split * (kS / kSplits);           // 128 rows per split
  const float* pkb = pk + (size_t)b * kS * kM;
  const bf16* hbb  = hb + (size_t)b * kS * kD;
  const int tid = threadIdx.x;
  const int tx = tid & 15, ty = tid >> 4;
  const bool do_pks = (blockIdx.x == 0);
  float lsum0 = 0.f, lsum1 = 0.f, lsum2 = 0.f, lsum3 = 0.f;
  const int mc = (tid * 4) & 63;
  float4 acc[4][4];
#pragma unroll
  for (int i = 0; i < 4; ++i)
#pragma unroll
    for (int j = 0; j < 4; ++j) acc[i][j] = make_float4(0.f, 0.f, 0.f, 0.f);

  for (int s0 = s_beg; s0 < s_beg + kS / kSplits; s0 += 16) {
    {
      int sr = tid >> 4;
      float4 v = *(const float4*)&pkb[(size_t)(s0 + sr) * kM + mc];
      *(float4*)&pkS[sr][mc] = v;
      if (do_pks) { lsum0 += v.x; lsum1 += v.y; lsum2 += v.z; lsum3 += v.w; }
    }
#pragma unroll
    for (int p = 0; p < 2; ++p) {
      int idx = p * 256 + tid;
      int sr = idx >> 5, dc8 = idx & 31;
      uint4 raw = *(const uint4*)&hbb[(size_t)(s0 + sr) * kD + d0 + dc8 * 8];
      float4 f0, f1;
      f0.x = __uint_as_float(raw.x << 16);
      f0.y = __uint_as_float(raw.x & 0xffff0000u);
      f0.z = __uint_as_float(raw.y << 16);
      f0.w = __uint_as_float(raw.y & 0xffff0000u);
      f1.x = __uint_as_float(raw.z << 16);
      f1.y = __uint_as_float(raw.z & 0xffff0000u);
      f1.z = __uint_as_float(raw.w << 16);
      f1.w = __uint_as_float(raw.w & 0xffff0000u);
      *(float4*)&vS[sr][dc8 * 8]     = f0;
      *(float4*)&vS[sr][dc8 * 8 + 4] = f1;
    }
    __syncthreads();
#pragma unroll
    for (int sr = 0; sr < 16; ++sr) {
      float a[4];
#pragma unroll
      for (int i = 0; i < 4; ++i) a[i] = pkS[sr][ty * 4 + i];
      float4 bv4[4];
#pragma unroll
      for (int j = 0; j < 4; ++j) bv4[j] = *(const float4*)&vS[sr][j * 64 + tx * 4];
#pragma unroll
      for (int i = 0; i < 4; ++i)
#pragma unroll
        for (int j = 0; j < 4; ++j) {
          acc[i][j].x += a[i] * bv4[j].x;
          acc[i][j].y += a[i] * bv4[j].y;
          acc[i][j].z += a[i] * bv4[j].z;
          acc[i][j].w += a[i] * bv4[j].w;
        }
    }
    __syncthreads();
  }
  if (do_pks) {
    atomicAdd(&pks[b * kM + mc + 0], lsum0);
    atomicAdd(&pks[b * kM + mc + 1], lsum1);
    atomicAdd(&pks[b * kM + mc + 2], lsum2);
    atomicAdd(&pks[b * kM + mc + 3], lsum3);
  }
  float* pp = part + (((size_t)split * kB + b) * kM) * kD;
#pragma unroll
  for (int i = 0; i < 4; ++i)
#pragma unroll
    for (int j = 0; j < 4; ++j)
      *(float4*)&pp[(size_t)(ty * 4 + i) * kD + d0 + j * 64 + tx * 4] = acc[i][j];
}

__global__ __launch_bounds__(256) void kvh_reduce_kernel(const float* __restrict__ part,
                                                         bf16* __restrict__ kvhb) {
  int gid = blockIdx.x * 256 + threadIdx.x;
  float4 s = make_float4(0.f, 0.f, 0.f, 0.f);
#pragma unroll
  for (int sp = 0; sp < kSplits; ++sp) {
    float4 p = ((const float4*)part)[(size_t)sp * (kB * kM * kD / 4) + gid];
    s.x += p.x; s.y += p.y; s.z += p.z; s.w += p.w;
  }
  ushort4 u;
  u.x = f2bf_u16(s.x); u.y = f2bf_u16(s.y);
  u.z = f2bf_u16(s.z); u.w = f2bf_u16(s.w);
  ((ushort4*)kvhb)[gid] = u;
}

// ---------------------------------------------------------------------------
__global__ __launch_bounds__(256) void zero_pks_kernel(float* __restrict__ p) {
  ((float4*)p)[threadIdx.x] = make_float4(0.f, 0.f, 0.f, 0.f);
}

// ---------------------------------------------------------------------------
// Fused attention-output + z + LayerNorm.
// ---------------------------------------------------------------------------
__global__ __launch_bounds__(256) void att_ln_kernel(
    const float* __restrict__ pq, const float* __restrict__ kvo,
    const float* __restrict__ pks, const float* __restrict__ bo,
    const float* __restrict__ g, const float* __restrict__ bb,
    bf16* __restrict__ out) {
  __shared__ float pqS[32][68];
  __shared__ float kvS[16][520];
  const int s0 = blockIdx.x * 32, b = blockIdx.y;
  const int tid = threadIdx.x;
  const int tx = tid & 15, ty = tid >> 4;

#pragma unroll
  for (int i = 0; i < 2; ++i) {
    int f4 = tid + i * 256;
    int r = f4 >> 4, c = (f4 & 15) * 4;
    *(float4*)&pqS[r][c] = *(const float4*)&pq[((size_t)(b * kS + s0 + r)) * kM + c];
  }

  float4 acc[2][8];
#pragma unroll
  for (int i = 0; i < 2; ++i)
#pragma unroll
    for (int j = 0; j < 8; ++j) acc[i][j] = make_float4(0.f, 0.f, 0.f, 0.f);

  for (int m0 = 0; m0 < kM; m0 += 16) {
#pragma unroll
    for (int p = 0; p < 8; ++p) {
      int idx = p * 256 + tid;
      int sr = idx >> 7, c4 = idx & 127;
      *(float4*)&kvS[sr][c4 * 4] =
          *(const float4*)&kvo[((size_t)b * kM + m0 + sr) * kD + c4 * 4];
    }
    __syncthreads();
#pragma unroll
    for (int mm = 0; mm < 16; ++mm) {
      float a0 = pqS[ty * 2 + 0][m0 + mm];
      float a1 = pqS[ty * 2 + 1][m0 + mm];
#pragma unroll
      for (int j = 0; j < 8; ++j) {
        float4 bv = *(const float4*)&kvS[mm][j * 64 + tx * 4];
        acc[0][j].x += a0 * bv.x; acc[0][j].y += a0 * bv.y;
        acc[0][j].z += a0 * bv.z; acc[0][j].w += a0 * bv.w;
        acc[1][j].x += a1 * bv.x; acc[1][j].y += a1 * bv.y;
        acc[1][j].z += a1 * bv.z; acc[1][j].w += a1 * bv.w;
      }
    }
    __syncthreads();
  }

  // z inline: each of the row's 16 lanes covers 4 m-values, 16-lane reduce.
  float4 pk4 = *(const float4*)&pks[b * kM + tx * 4];
  float z0 = pqS[ty * 2 + 0][tx * 4 + 0] * pk4.x + pqS[ty * 2 + 0][tx * 4 + 1] * pk4.y +
             pqS[ty * 2 + 0][tx * 4 + 2] * pk4.z + pqS[ty * 2 + 0][tx * 4 + 3] * pk4.w;
  float z1 = pqS[ty * 2 + 1][tx * 4 + 0] * pk4.x + pqS[ty * 2 + 1][tx * 4 + 1] * pk4.y +
             pqS[ty * 2 + 1][tx * 4 + 2] * pk4.z + pqS[ty * 2 + 1][tx * 4 + 3] * pk4.w;
  z0 += __shfl_xor(z0, 1); z0 += __shfl_xor(z0, 2);
  z0 += __shfl_xor(z0, 4); z0 += __shfl_xor(z0, 8);
  z1 += __shfl_xor(z1, 1); z1 += __shfl_xor(z1, 2);
  z1 += __shfl_xor(z1, 4); z1 += __shfl_xor(z1, 8);
  float zi0 = 1.0f / (z0 + 1e-6f);
  float zi1 = 1.0f / (z1 + 1e-6f);

#pragma unroll
  for (int j = 0; j < 8; ++j) {
    float4 bo4 = *(const float4*)&bo[j * 64 + tx * 4];
    acc[0][j].x = acc[0][j].x * zi0 + bo4.x; acc[0][j].y = acc[0][j].y * zi0 + bo4.y;
    acc[0][j].z = acc[0][j].z * zi0 + bo4.z; acc[0][j].w = acc[0][j].w * zi0 + bo4.w;
    acc[1][j].x = acc[1][j].x * zi1 + bo4.x; acc[1][j].y = acc[1][j].y * zi1 + bo4.y;
    acc[1][j].z = acc[1][j].z * zi1 + bo4.z; acc[1][j].w = acc[1][j].w * zi1 + bo4.w;
  }

#pragma unroll
  for (int i = 0; i < 2; ++i) {
    float s = 0.f;
#pragma unroll
    for (int j = 0; j < 8; ++j)
      s += (acc[i][j].x + acc[i][j].y) + (acc[i][j].z + acc[i][j].w);
    s += __shfl_xor(s, 1); s += __shfl_xor(s, 2);
    s += __shfl_xor(s, 4); s += __shfl_xor(s, 8);
    float mean = s * (1.0f / kD);
    float v2 = 0.f;
#pragma unroll
    for (int j = 0; j < 8; ++j) {
      float dx = acc[i][j].x - mean, dy = acc[i][j].y - mean;
      float dz = acc[i][j].z - mean, dw = acc[i][j].w - mean;
      v2 += (dx * dx + dy * dy) + (dz * dz + dw * dw);
    }
    v2 += __shfl_xor(v2, 1); v2 += __shfl_xor(v2, 2);
    v2 += __shfl_xor(v2, 4); v2 += __shfl_xor(v2, 8);
    float rstd = rsqrtf(v2 * (1.0f / kD) + 1e-5f);
    size_t rowoff = ((size_t)(b * kS + s0 + ty * 2 + i)) * kD;
#pragma unroll
    for (int j = 0; j < 8; ++j) {
      int col = j * 64 + tx * 4;
      float4 g4 = *(const float4*)&g[col];
      float4 b4 = *(const float4*)&bb[col];
      ushort4 u;
      u.x = f2bf_u16((acc[i][j].x - mean) * rstd * g4.x + b4.x);
      u.y = f2bf_u16((acc[i][j].y - mean) * rstd * g4.y + b4.y);
      u.z = f2bf_u16((acc[i][j].z - mean) * rstd * g4.z + b4.z);
      u.w = f2bf_u16((acc[i][j].w - mean) * rstd * g4.w + b4.w);
      *(ushort4*)&out[rowoff + col] = u;
    }
  }
}

// ---------------------------------------------------------------------------
__global__ __launch_bounds__(256) void cls_kernel(const float* __restrict__ h,
    const float* __restrict__ Wc1, const float* __restrict__ bc1,
    const float* __restrict__ Wc2, const float* __restrict__ bc2,
    float* __restrict__ out) {
  __shared__ float r0[4], r1[4];
  int b = blockIdx.x;
  int j = threadIdx.x;
  const float* p = h + (size_t)b * kS * kD;
  float acc = bc1[j];
  for (int i = 0; i < kD; ++i) acc += p[i] * Wc1[i * (kD / 2) + j];
  acc = fmaxf(acc, 0.f);
  float p0 = acc * Wc2[j * kC + 0];
  float p1 = acc * Wc2[j * kC + 1];
#pragma unroll
  for (int off = 32; off; off >>= 1) {
    p0 += __shfl_down(p0, off);
    p1 += __shfl_down(p1, off);
  }
  if ((j & 63) == 0) { r0[j >> 6] = p0; r1[j >> 6] = p1; }
  __syncthreads();
  if (j == 0) {
    out[b * kC + 0] = r0[0] + r0[1] + r0[2] + r0[3] + bc2[0];
    out[b * kC + 1] = r1[0] + r1[1] + r1[2] + r1[3] + bc2[1];
  }
}

// ---------------------------------------------------------------------------
extern "C" void kernel_launch(void* const* d_in, const int* in_sizes, int n_in,
                              void* d_out, int out_size, void* d_ws, size_t ws_size,
                              hipStream_t stream) {
  const int*   x    = (const int*)  d_in[0];
  const float* emb  = (const float*)d_in[1];
  const float* pos  = (const float*)d_in[2];
  const float* Wq   = (const float*)d_in[3];
  const float* bq   = (const float*)d_in[4];
  const float* Wk   = (const float*)d_in[5];
  const float* bk   = (const float*)d_in[6];
  const float* Wv   = (const float*)d_in[7];
  const float* bv   = (const float*)d_in[8];
  const float* P    = (const float*)d_in[9];
  const float* Wo   = (const float*)d_in[10];
  const float* bo   = (const float*)d_in[11];
  const float* ln_g = (const float*)d_in[12];
  const float* ln_b = (const float*)d_in[13];
  const float* W1   = (const float*)d_in[14];
  const float* b1   = (const float*)d_in[15];
  const float* W2   = (const float*)d_in[16];
  const float* b2   = (const float*)d_in[17];
  const float* Wc1  = (const float*)d_in[18];
  const float* bc1  = (const float*)d_in[19];
  const float* Wc2  = (const float*)d_in[20];
  const float* bc2  = (const float*)d_in[21];
  float* out = (float*)d_out;

  // fp32 region
  float* h    = (float*)d_ws;                    // 64 MB
  float* t0   = h    + (size_t)kBS * kD;         // 64 MB (F aliases)
  float* pq   = t0   + (size_t)kBS * kD;         // 8 MB
  float* pk   = pq   + (size_t)kBS * kM;         // 8 MB
  float* kvo  = pk   + (size_t)kBS * kM;         // 2 MB
  float* pks  = kvo  + (size_t)kB * kM * kD;
  float* bqp  = pks  + (size_t)kB * kM;          // kL x kM
  float* bkp  = bqp  + (size_t)kL * kM;
  float* bvWo = bkp  + (size_t)kL * kM;          // kL x kD
  float* zeros= bvWo + (size_t)kL * kD;
  // bf16 region (per-layer weight buffers x kL, prepped once up front)
  bf16* hb    = (bf16*)(zeros + kD);             // 32 MB
  bf16* ab    = hb + (size_t)kBS * kD;           // 32 MB (kvh partials alias)
  bf16* Wqpt  = ab  + (size_t)kBS * kD;
  bf16* Wkpt  = Wqpt + (size_t)kL * kM * kD;
  bf16* Wot   = Wkpt + (size_t)kL * kM * kD;
  bf16* Wvc   = Wot + (size_t)kL * kD * kD;
  bf16* WvWot = Wvc + (size_t)kL * kD * kD;
  bf16* W1t   = WvWot + (size_t)kL * kD * kD;
  bf16* W2t   = W1t + (size_t)kL * kD * kH;
  bf16* kvhb  = W2t + (size_t)kL * kH * kD;
  bf16* F     = (bf16*)t0;
  float* kvpart = (float*)ab;                    // 32 MB (16 splits)

  zero512_kernel<<<1, 256, 0, stream>>>(zeros);
  embed_kernel<<<kBS * (kD / 4) / 256, 256, 0, stream>>>(x, emb, pos, h, hb);

  // ---- batched weight prep for ALL layers ----
  wfold_dual_kernel<<<kL * 256, 256, 0, stream>>>(Wq, Wk, P, Wqpt, Wkpt);
  bfold_kernel<<<1, 128 * kL, 0, stream>>>(bq, bk, P, bqp, bkp);
  transpose_cast_kernel<<<dim3(kD / 32, kD / 32, kL), 256, 0, stream>>>(
      Wo, Wot, kD, kD, (size_t)kD * kD, (size_t)kD * kD);
  cast_bf16_kernel<<<kL * kD * kD / 1024, 256, 0, stream>>>(Wv, Wvc);
  mfma_gemm<32, 64, 0, false, false, false, true><<<dim3(8, 4, kL), 256, 0, stream>>>(
      Wot, Wvc, zeros, nullptr, nullptr, nullptr, nullptr, WvWot,
      (size_t)kD * kD, (size_t)kD * kD, (size_t)kD * kD, kD, kD);
  bvwo_kernel<<<dim3(kD / 64, kL), 256, 0, stream>>>(bv, Wo, bvWo);
  transpose_cast_kernel<<<dim3(kD / 32, kH / 32, kL), 256, 0, stream>>>(
      W1, W1t, kD, kH, (size_t)kD * kH, (size_t)kD * kH);
  transpose_cast_kernel<<<dim3(kH / 32, kD / 32, kL), 256, 0, stream>>>(
      W2, W2t, kH, kD, (size_t)kH * kD, (size_t)kH * kD);

  for (int l = 0; l < kL; ++l) {
    // ---- attention (folded) ----
    skinny_dual_gemm<<<kBS / 64, 256, 0, stream>>>(
        hb, Wqpt + (size_t)l * kM * kD, Wkpt + (size_t)l * kM * kD,
        bqp + (size_t)l * kM, bkp + (size_t)l * kM, pq, pk);
    zero_pks_kernel<<<1, 256, 0, stream>>>(pks);
    kvh_split_kernel<<<dim3(kD / 256, kB, kSplits), 256, 0, stream>>>(pk, hb, kvpart, pks);
    kvh_reduce_kernel<<<kB * kM * kD / 1024, 256, 0, stream>>>(kvpart, kvhb);
    mfma_gemm<32, 64, 0, false, true, true, false><<<dim3(8, 8), 256, 0, stream>>>(
        kvhb, WvWot + (size_t)l * kD * kD, nullptr, pks, bvWo + (size_t)l * kD,
        nullptr, kvo, nullptr, 0, 0, 0, kD, kD);
    att_ln_kernel<<<dim3(kS / 32, kB), 256, 0, stream>>>(
        pq, kvo, pks, bo + l * kD, ln_g + l * kD, ln_b + l * kD, ab);
    // ---- FFN in 2 row-chunks of 16384, counted-vmcnt pipelined GEMMs ----
    for (int c = 0; c < 2; ++c) {
      size_t ro = (size_t)c * 16384;
      mfma_gemm_cnt<2, false, false, true><<<dim3(kH / 128, 16384 / 128), 512, 0, stream>>>(
          ab + ro * kD, W1t + (size_t)l * kD * kH, b1 + l * kH, nullptr, nullptr, F, kD, kH);
      mfma_gemm_cnt<0, true, true, true><<<dim3(kD / 128, 16384 / 128), 512, 0, stream>>>(
          F, W2t + (size_t)l * kH * kD, b2 + l * kD, h + ro * kD, h + ro * kD, hb + ro * kD, kH, kD);
    }
  }

  cls_kernel<<<kB, 256, 0, stream>>>(h, Wc1, bc1, Wc2, bc2, out);
}